// Round 20
// baseline (1043.673 us; speedup 1.0000x reference)
//
#include <hip/hip_runtime.h>
#include <math.h>

#define S_LEN 2048
#define DHEAD 64
#define NBINS 512
#define BPL (NBINS / 64)
#define CANDMAX 48
#define NBH 64
#define NROWS (NBH * S_LEN)                 // 32768
#define VT_BYTES (64ull * DHEAD * S_LEN * 2)  // 16 MB fp16 V^T

typedef _Float16 f16x8 __attribute__((ext_vector_type(8)));
typedef _Float16 f16x4 __attribute__((ext_vector_type(4)));
typedef float    f32x4 __attribute__((ext_vector_type(4)));

// ---------------------------------------------------------------------------
// Kernel P: V fp32 -> V^T fp16 via LDS-tile transpose (coalesced both sides).
// ---------------------------------------------------------------------------
__global__ __launch_bounds__(256)
void prep_vt(const float* __restrict__ V, _Float16* __restrict__ VT) {
  __shared__ _Float16 trans[64][72];
  const int bh  = (int)blockIdx.x >> 5;
  const int kt  = (int)blockIdx.x & 31;
  const int t   = (int)threadIdx.x;
  const int key0 = kt * 64;
  const float* Vb = V + ((size_t)bh * S_LEN + key0) * DHEAD;

  {
    const int key = t >> 2;
    const int dc  = t & 3;
    #pragma unroll
    for (int i = 0; i < 4; ++i) {
      int d = dc * 16 + i * 4;
      float4 v4 = *(const float4*)(Vb + (size_t)key * DHEAD + d);
      trans[d + 0][key] = (_Float16)v4.x;
      trans[d + 1][key] = (_Float16)v4.y;
      trans[d + 2][key] = (_Float16)v4.z;
      trans[d + 3][key] = (_Float16)v4.w;
    }
  }
  __syncthreads();
  {
    const int dim = t >> 2;
    const int kc  = t & 3;
    _Float16* dst = VT + ((size_t)bh * DHEAD + dim) * S_LEN + key0 + kc * 16;
    f16x8 a, b;
    #pragma unroll
    for (int j = 0; j < 8; ++j) { a[j] = trans[dim][kc * 16 + j];
                                  b[j] = trans[dim][kc * 16 + 8 + j]; }
    *(f16x8*)(dst)     = a;
    *(f16x8*)(dst + 8) = b;
  }
}

// ---------------------------------------------------------------------------
// Kernel A (proven): QK^T via 4-term hi/lo fp16 MFMA. XCD-swizzled.
// Block = 256 thr (4 waves) = 64 q-rows x 256 keys. Grid = rows/8.
// ---------------------------------------------------------------------------
__global__ __launch_bounds__(256, 4)
void qk_kernel(const float* __restrict__ Q, const float* __restrict__ K,
               float* __restrict__ Sws, int row0) {
  __shared__ __align__(16) char kbuf[32768];   // hi 16KB | lo 16KB
  f16x8* Khw = (f16x8*)kbuf;
  f16x8* Klw = (f16x8*)(kbuf + 16384);

  const int tid  = (int)threadIdx.x;
  const int lane = tid & 63;
  const int wid  = tid >> 6;
  const int nxl  = (int)gridDim.x >> 3;
  const int xcd  = (int)blockIdx.x & 7;
  const int lb   = (int)blockIdx.x >> 3;
  const int rb   = lb >> 3;
  const int kb   = lb & 7;                      // key eighth
  const int rowl = xcd * (nxl * 8) + rb * 64 + wid * 16;
  const int rowg = row0 + rowl;
  const int bh   = rowg >> 11;
  const int key0 = kb * 256;

  const int g = lane >> 4;
  const int m = lane & 15;

  f16x8 a_hi0, a_lo0, a_hi1, a_lo1;
  {
    const float* Qrow = Q + (size_t)(rowg + m) * DHEAD;
    float4 qa = *(const float4*)(Qrow + g * 8);
    float4 qb = *(const float4*)(Qrow + g * 8 + 4);
    float4 qc = *(const float4*)(Qrow + 32 + g * 8);
    float4 qd = *(const float4*)(Qrow + 32 + g * 8 + 4);
    float x[16] = {qa.x,qa.y,qa.z,qa.w, qb.x,qb.y,qb.z,qb.w,
                   qc.x,qc.y,qc.z,qc.w, qd.x,qd.y,qd.z,qd.w};
    #pragma unroll
    for (int j = 0; j < 8; ++j) {
      _Float16 h0 = (_Float16)x[j];
      a_hi0[j] = h0;  a_lo0[j] = (_Float16)(x[j] - (float)h0);
      _Float16 h1 = (_Float16)x[8 + j];
      a_hi1[j] = h1;  a_lo1[j] = (_Float16)(x[8 + j] - (float)h1);
    }
  }

  const float* Kb = K + (size_t)bh * (S_LEN * DHEAD);
  float* Srow = Sws + (size_t)rowl * S_LEN;

  const int skey  = tid >> 1;
  const int shalf = tid & 1;
  const int ssw   = skey & 7;

  float4 pf[8];
  {
    const float4* kr = (const float4*)(Kb + (size_t)(key0 + skey) * DHEAD + shalf * 32);
    #pragma unroll
    for (int j = 0; j < 8; ++j) pf[j] = kr[j];
  }

  #pragma unroll
  for (int t = 0; t < 2; ++t) {
    #pragma unroll
    for (int jj = 0; jj < 4; ++jj) {
      float x[8] = {pf[2*jj].x, pf[2*jj].y, pf[2*jj].z, pf[2*jj].w,
                    pf[2*jj+1].x, pf[2*jj+1].y, pf[2*jj+1].z, pf[2*jj+1].w};
      f16x8 hi, lo;
      #pragma unroll
      for (int j = 0; j < 8; ++j) {
        _Float16 h = (_Float16)x[j];
        hi[j] = h;
        lo[j] = (_Float16)(x[j] - (float)h);
      }
      int c = shalf * 4 + jj;
      Khw[skey * 8 + (c ^ ssw)] = hi;
      Klw[skey * 8 + (c ^ ssw)] = lo;
    }
    if (t + 1 < 2) {
      const float4* kr = (const float4*)(Kb + (size_t)(key0 + 128 + skey) * DHEAD + shalf * 32);
      #pragma unroll
      for (int j = 0; j < 8; ++j) pf[j] = kr[j];
    }
    __syncthreads();

    const f16x8* Kh = (const f16x8*)kbuf;
    const f16x8* Kl = (const f16x8*)(kbuf + 16384);
    int slot0 = ( g      ^ (m & 7));
    int slot1 = ((4 + g) ^ (m & 7));
    #pragma unroll
    for (int p = 0; p < 8; ++p) {
      int keyr = p * 16 + m;
      f16x8 b_hi0 = Kh[keyr * 8 + slot0];
      f16x8 b_hi1 = Kh[keyr * 8 + slot1];
      f16x8 b_lo0 = Kl[keyr * 8 + slot0];
      f16x8 b_lo1 = Kl[keyr * 8 + slot1];
      f32x4 acc = {0.f, 0.f, 0.f, 0.f};
      acc = __builtin_amdgcn_mfma_f32_16x16x32_f16(a_hi0, b_hi0, acc, 0, 0, 0);
      acc = __builtin_amdgcn_mfma_f32_16x16x32_f16(a_hi1, b_hi1, acc, 0, 0, 0);
      acc = __builtin_amdgcn_mfma_f32_16x16x32_f16(a_hi0, b_lo0, acc, 0, 0, 0);
      acc = __builtin_amdgcn_mfma_f32_16x16x32_f16(a_hi1, b_lo1, acc, 0, 0, 0);
      acc = __builtin_amdgcn_mfma_f32_16x16x32_f16(a_lo0, b_hi0, acc, 0, 0, 0);
      acc = __builtin_amdgcn_mfma_f32_16x16x32_f16(a_lo1, b_hi1, acc, 0, 0, 0);
      acc = __builtin_amdgcn_mfma_f32_16x16x32_f16(a_lo0, b_lo0, acc, 0, 0, 0);
      acc = __builtin_amdgcn_mfma_f32_16x16x32_f16(a_lo1, b_lo1, acc, 0, 0, 0);
      int col = key0 + t * 128 + p * 16 + m;
      #pragma unroll
      for (int rg = 0; rg < 4; ++rg)
        __builtin_nontemporal_store(acc[rg] * 0.125f,
            &Srow[(size_t)(g * 4 + rg) * S_LEN + col]);
    }
    __syncthreads();
  }
}

// ---------------------------------------------------------------------------
// Kernel B v2: 1024 thr (16 waves), 16 rows/block. Selection: 1 row/wave
// (R16 logic, rr-loop removed). PV: 4-way key split (wave = kq*4+dg),
// 2 MFMAs/kt, 4-way LDS reduction. 2 blocks/CU x 16 waves = full occupancy.
// LDS 35.9KB: [0,32768) union{hist u32[16][512] | pbuf 8KB @0, redS @8192}
//             [32768) candS[16][48] | candCnt[16] | psumS[16]
// ---------------------------------------------------------------------------
__global__ __launch_bounds__(1024, 2)
void selmm_kernel(const float* __restrict__ Sws, const _Float16* __restrict__ VT,
                  const int* __restrict__ nkp, float* __restrict__ Out, int row0) {
  __shared__ __align__(16) char smem[35968];
  unsigned* histS  = (unsigned*)smem;                  // [16][512] (phase 1)
  char*     pbuf   = smem;                             // 8KB P tile (phase 2)
  float4*   redS   = (float4*)(smem + 8192);           // [3][4][64] (phase 2)
  float*    candS  = (float*)(smem + 32768);           // [16][48]
  unsigned* candCnt= (unsigned*)(smem + 35840);        // [16]
  float*    psumS  = (float*)(smem + 35904);           // [16]

  const int tid  = (int)threadIdx.x;
  const int lane = tid & 63;
  const int wid  = tid >> 6;                           // 0..15
  const int nxl  = (int)gridDim.x >> 3;
  const int xcd  = (int)blockIdx.x & 7;
  const int lbk  = (int)blockIdx.x >> 3;
  const int rowlb = xcd * (nxl * 16) + lbk * 16;       // chunk-local base
  const int rowgb = row0 + rowlb;                      // global base (16-aligned)
  const int bh    = rowgb >> 11;

  int nk = nkp[0];
  if (nk > S_LEN) nk = S_LEN;

  unsigned* hw = histS + wid * NBINS;
  float*    cw = candS + wid * CANDMAX;
  float sarr[32];
  float thr, vmx;

  // ---------------- phase 1: selection, 1 row per wave (row = wid) --------
  {
    const f32x4* S4 = (const f32x4*)(Sws + (size_t)(rowlb + wid) * S_LEN);
    #pragma unroll
    for (int j = 0; j < 8; ++j) {
      f32x4 v4 = __builtin_nontemporal_load(S4 + j * 64 + lane);
      sarr[j*4+0] = v4[0]; sarr[j*4+1] = v4[1];
      sarr[j*4+2] = v4[2]; sarr[j*4+3] = v4[3];
    }
  }

  float vmax = -INFINITY, vmin = INFINITY;
  #pragma unroll
  for (int q = 0; q < 32; ++q) {
    vmax = fmaxf(vmax, sarr[q]); vmin = fminf(vmin, sarr[q]);
  }
  #pragma unroll
  for (int off = 32; off >= 1; off >>= 1) {
    vmax = fmaxf(vmax, __shfl_xor(vmax, off));
    vmin = fminf(vmin, __shfl_xor(vmin, off));
  }

  float thresh = -INFINITY;
  if (nk > 0) {
    float range = vmax - vmin;
    float scale = (range > 0.f) ? ((float)NBINS / range) : 0.f;
    float boff  = vmin * scale;

    #pragma unroll
    for (int i2 = 0; i2 < BPL; ++i2) hw[(i2 << 6) | lane] = 0u;
    #pragma unroll
    for (int q = 0; q < 32; ++q) {
      int bb = (int)fmaf(sarr[q], scale, -boff);
      bb = bb < 0 ? 0 : (bb > NBINS - 1 ? NBINS - 1 : bb);
      atomicAdd(&hw[((bb & 7) << 6) | (bb >> 3)], 1u);       // transposed bins
    }

    unsigned A = 0;
    #pragma unroll
    for (int i2 = 0; i2 < BPL; ++i2) A += hw[(i2 << 6) | lane];
    unsigned ssum = A;
    #pragma unroll
    for (int off = 1; off <= 32; off <<= 1) {
      unsigned u = (unsigned)__shfl_down((int)ssum, off);
      if (lane + off < 64) ssum += u;
    }
    unsigned cum = ssum - A;
    int bsel = -1; int mloc = 0; int nbloc = 0;
    #pragma unroll
    for (int i2 = BPL - 1; i2 >= 0; --i2) {
      unsigned c0 = cum; cum += hw[(i2 << 6) | lane];
      if (bsel < 0 && c0 < (unsigned)nk && cum >= (unsigned)nk) {
        bsel = (lane << 3) | i2; mloc = nk - (int)c0; nbloc = (int)(cum - c0);
      }
    }
    unsigned long long fm = __ballot(bsel >= 0);
    int srcl = __ffsll(fm) - 1;
    bsel = __shfl(bsel, srcl);
    int mth  = __shfl(mloc, srcl);
    int nbin = __shfl(nbloc, srcl);

    if (nbin <= CANDMAX) {
      if (lane == 0) candCnt[wid] = 0u;
      __builtin_amdgcn_wave_barrier();
      #pragma unroll
      for (int q = 0; q < 32; ++q) {
        int bb = (int)fmaf(sarr[q], scale, -boff);
        bb = bb < 0 ? 0 : (bb > NBINS - 1 ? NBINS - 1 : bb);
        if (bb == bsel) {
          unsigned ix = atomicAdd(&candCnt[wid], 1u);
          if (ix < CANDMAX) cw[ix] = sarr[q];
        }
      }
      __builtin_amdgcn_wave_barrier();
      float prev = INFINITY, kth = -INFINITY;
      int got = 0, guard = 0;
      while (got < mth && guard++ <= CANDMAX) {
        float best = -INFINITY;
        for (int i = 0; i < nbin; ++i) {
          float v = cw[i];
          if (v < prev && v > best) best = v;
        }
        int ce = 0;
        for (int i = 0; i < nbin; ++i) if (cw[i] == best) ce++;
        got += ce; prev = best; kth = best;
      }
      thresh = kth;
    } else {
      // exact shfl-chain fallback (pathological tie mass)
      unsigned inbin = 0;
      #pragma unroll
      for (int q = 0; q < 32; ++q) {
        int bb = (int)fmaf(sarr[q], scale, -boff);
        bb = bb < 0 ? 0 : (bb > NBINS - 1 ? NBINS - 1 : bb);
        if (bb == bsel) inbin |= (1u << q);
      }
      while (true) {
        float cmax = -INFINITY;
        #pragma unroll
        for (int q = 0; q < 32; ++q) if (inbin & (1u << q)) cmax = fmaxf(cmax, sarr[q]);
        #pragma unroll
        for (int off = 32; off >= 1; off >>= 1) cmax = fmaxf(cmax, __shfl_xor(cmax, off));
        int cnt = 0;
        #pragma unroll
        for (int q = 0; q < 32; ++q) if ((inbin & (1u << q)) && sarr[q] == cmax) cnt++;
        #pragma unroll
        for (int off = 32; off >= 1; off >>= 1) cnt += __shfl_xor(cnt, off);
        if (mth <= cnt) { thresh = cmax; break; }
        mth -= cnt;
        #pragma unroll
        for (int q = 0; q < 32; ++q) if ((inbin & (1u << q)) && sarr[q] == cmax) inbin &= ~(1u << q);
      }
    }
  }
  thr = thresh; vmx = vmax;

  {
    float psum = 0.f;
    #pragma unroll
    for (int q = 0; q < 32; ++q) {
      float s = sarr[q];
      psum += (s >= thr) ? __expf(s - vmx) : 0.f;
    }
    #pragma unroll
    for (int off = 32; off >= 1; off >>= 1) psum += __shfl_xor(psum, off);
    if (lane == 0) psumS[wid] = psum;
  }
  __syncthreads();            // selection done; hist dead

  // ---------------- phase 2: dense masked-P x V via MFMA, 4-way keys ------
  const int g   = lane >> 4;
  const int n16 = lane & 15;
  const int kq  = wid >> 2;         // key quarter (0..3)
  const int dg  = wid & 3;          // dim group: dims dg*16..+15
  const _Float16* VTb = VT + (size_t)bh * (DHEAD * S_LEN);
  f32x4 acc = {0.f, 0.f, 0.f, 0.f};

  #pragma unroll
  for (int kt = 0; kt < 8; ++kt) {
    // each wave writes its own row's P slice (row = wid)
    {
      f16x4 pv;
      #pragma unroll
      for (int c = 0; c < 4; ++c) {
        float s = sarr[kt * 4 + c];
        float p = (s >= thr) ? __expf(s - vmx) : 0.f;
        pv[c] = (_Float16)p;
      }
      *(f16x4*)(pbuf + ((wid * 512 + lane * 8) ^ ((wid & 7) << 4))) = pv;
    }
    __syncthreads();
    #pragma unroll
    for (int s2 = 0; s2 < 2; ++s2) {
      int slice = kq * 2 + s2;        // 32-key slice within 256-tile
      f16x8 af = *(const f16x8*)(pbuf +
          ((n16 * 512 + slice * 64 + g * 16) ^ ((n16 & 7) << 4)));
      f16x8 bf = *(const f16x8*)(VTb + (size_t)(dg * 16 + n16) * S_LEN +
                                 kt * 256 + kq * 64 + s2 * 32 + g * 8);
      acc = __builtin_amdgcn_mfma_f32_16x16x32_f16(af, bf, acc, 0, 0, 0);
    }
    __syncthreads();
  }

  // 4-way reduction across key quarters, scale by 1/psum, write out
  if (kq > 0) {
    redS[((kq - 1) * 4 + dg) * 64 + lane] = make_float4(acc[0], acc[1], acc[2], acc[3]);
  }
  __syncthreads();
  if (kq == 0) {
    float tot[4] = {acc[0], acc[1], acc[2], acc[3]};
    #pragma unroll
    for (int p = 0; p < 3; ++p) {
      float4 o = redS[(p * 4 + dg) * 64 + lane];
      tot[0] += o.x; tot[1] += o.y; tot[2] += o.z; tot[3] += o.w;
    }
    #pragma unroll
    for (int rg = 0; rg < 4; ++rg) {
      int row = g * 4 + rg;                      // C-row = P row
      float val = tot[rg] / psumS[row];
      Out[(size_t)(rowgb + row) * DHEAD + dg * 16 + n16] = val;
    }
  }
}

// ---------------------------------------------------------------------------
// Fallback monolithic kernel (round-3, proven) for tiny ws_size
// ---------------------------------------------------------------------------
#define TQ 16
#define KT 128
#define NTILES (S_LEN / KT)
#define THREADS 512
#define LCAP 256
#define SOFF   0
#define KHI    131072
#define KLO    147456
#define HOFF   131072
#define KLOFF  147456
#define PLOFF  155648

__global__ __launch_bounds__(THREADS, 2)
void dpsa_kernel(const float* __restrict__ Q, const float* __restrict__ K,
                 const float* __restrict__ V, const int* __restrict__ nkp,
                 float* __restrict__ Out) {
  __shared__ __align__(16) char smem[163840];
  float* Sf = (float*)(smem + SOFF);

  const int tid  = (int)threadIdx.x;
  const int lane = tid & 63;
  const int wid  = tid >> 6;
  const int bid  = (int)blockIdx.x;
  const int bh   = bid >> 7;
  const int qblk = bid & 127;
  const size_t base = (size_t)bh * (size_t)(S_LEN * DHEAD);
  const float* Kbh = K + base;
  const float* Vbh = V + base;

  int nk = nkp[0];
  if (nk > S_LEN) nk = S_LEN;

  const int g = lane >> 4;
  const int m = lane & 15;

  f16x8 a_hi0, a_lo0, a_hi1, a_lo1;
  {
    const float* Qrow = Q + base + (size_t)(qblk * TQ + m) * DHEAD;
    float4 qa = *(const float4*)(Qrow + g * 8);
    float4 qb = *(const float4*)(Qrow + g * 8 + 4);
    float4 qc = *(const float4*)(Qrow + 32 + g * 8);
    float4 qd = *(const float4*)(Qrow + 32 + g * 8 + 4);
    float x[16] = {qa.x,qa.y,qa.z,qa.w, qb.x,qb.y,qb.z,qb.w,
                   qc.x,qc.y,qc.z,qc.w, qd.x,qd.y,qd.z,qd.w};
    #pragma unroll
    for (int j = 0; j < 8; ++j) {
      _Float16 h0 = (_Float16)x[j];
      a_hi0[j] = h0;  a_lo0[j] = (_Float16)(x[j] - (float)h0);
      _Float16 h1 = (_Float16)x[8 + j];
      a_hi1[j] = h1;  a_lo1[j] = (_Float16)(x[8 + j] - (float)h1);
    }
  }

  const f16x8* Kh = (const f16x8*)(smem + KHI);
  const f16x8* Kl = (const f16x8*)(smem + KLO);
  const int keyl = tid >> 2;
  const int q4i  = tid & 3;
  const int sw   = keyl & 7;

  float4 pf0, pf1, pf2, pf3;
  {
    const float4* Kg4 = (const float4*)Kbh;
    int idx = keyl * 16 + q4i * 4;
    pf0 = Kg4[idx]; pf1 = Kg4[idx + 1]; pf2 = Kg4[idx + 2]; pf3 = Kg4[idx + 3];
  }

  for (int t = 0; t < NTILES; ++t) {
    {
      float x[16] = {pf0.x,pf0.y,pf0.z,pf0.w, pf1.x,pf1.y,pf1.z,pf1.w,
                     pf2.x,pf2.y,pf2.z,pf2.w, pf3.x,pf3.y,pf3.z,pf3.w};
      f16x8 hi0, hi1, lo0, lo1;
      #pragma unroll
      for (int j = 0; j < 8; ++j) {
        _Float16 h0 = (_Float16)x[j];
        hi0[j] = h0;  lo0[j] = (_Float16)(x[j] - (float)h0);
        _Float16 h1 = (_Float16)x[8 + j];
        hi1[j] = h1;  lo1[j] = (_Float16)(x[8 + j] - (float)h1);
      }
      f16x8* KhwF = (f16x8*)(smem + KHI);
      f16x8* KlwF = (f16x8*)(smem + KLO);
      KhwF[keyl * 8 + ((q4i * 2)     ^ sw)] = hi0;
      KhwF[keyl * 8 + ((q4i * 2 + 1) ^ sw)] = hi1;
      KlwF[keyl * 8 + ((q4i * 2)     ^ sw)] = lo0;
      KlwF[keyl * 8 + ((q4i * 2 + 1) ^ sw)] = lo1;
    }
    if (t + 1 < NTILES) {
      const float4* Kg4 = (const float4*)(Kbh + (size_t)(t + 1) * (KT * DHEAD));
      int idx = keyl * 16 + q4i * 4;
      pf0 = Kg4[idx]; pf1 = Kg4[idx + 1]; pf2 = Kg4[idx + 2]; pf3 = Kg4[idx + 3];
    }
    __syncthreads();
    {
      int keyr = wid * 16 + m;
      int s0 = ( g      ^ (m & 7));
      int s1 = ((4 + g) ^ (m & 7));
      f16x8 b_hi0 = Kh[keyr * 8 + s0];
      f16x8 b_hi1 = Kh[keyr * 8 + s1];
      f16x8 b_lo0 = Kl[keyr * 8 + s0];
      f16x8 b_lo1 = Kl[keyr * 8 + s1];
      f32x4 acc = {0.f, 0.f, 0.f, 0.f};
      acc = __builtin_amdgcn_mfma_f32_16x16x32_f16(a_hi0, b_hi0, acc, 0, 0, 0);
      acc = __builtin_amdgcn_mfma_f32_16x16x32_f16(a_hi1, b_hi1, acc, 0, 0, 0);
      acc = __builtin_amdgcn_mfma_f32_16x16x32_f16(a_hi0, b_lo0, acc, 0, 0, 0);
      acc = __builtin_amdgcn_mfma_f32_16x16x32_f16(a_hi1, b_lo1, acc, 0, 0, 0);
      acc = __builtin_amdgcn_mfma_f32_16x16x32_f16(a_lo0, b_hi0, acc, 0, 0, 0);
      acc = __builtin_amdgcn_mfma_f32_16x16x32_f16(a_lo1, b_hi1, acc, 0, 0, 0);
      int keyabs = t * KT + wid * 16 + m;
      #pragma unroll
      for (int rg = 0; rg < 4; ++rg)
        Sf[(size_t)(g * 4 + rg) * S_LEN + keyabs] = acc[rg] * 0.125f;
    }
    __syncthreads();
  }

  unsigned* hw = (unsigned*)(smem + HOFF)  + wid * NBINS;
  unsigned* kl = (unsigned*)(smem + KLOFF) + wid * LCAP;
  float*    pl = (float*)(smem + PLOFF)    + wid * LCAP;
  const float4* S4 = (const float4*)(smem + SOFF);

  for (int rr = 0; rr < 2; ++rr) {
    const int row = wid * 2 + rr;
    float sarr[32];
    #pragma unroll
    for (int j = 0; j < 8; ++j) {
      float4 v4 = S4[row * (S_LEN / 4) + j * 64 + lane];
      sarr[j*4+0] = v4.x; sarr[j*4+1] = v4.y;
      sarr[j*4+2] = v4.z; sarr[j*4+3] = v4.w;
    }

    float vmax = -INFINITY, vmin = INFINITY;
    #pragma unroll
    for (int q = 0; q < 32; ++q) {
      vmax = fmaxf(vmax, sarr[q]); vmin = fminf(vmin, sarr[q]);
    }
    #pragma unroll
    for (int off = 32; off >= 1; off >>= 1) {
      vmax = fmaxf(vmax, __shfl_xor(vmax, off));
      vmin = fminf(vmin, __shfl_xor(vmin, off));
    }

    float thresh = -INFINITY;
    if (nk > 0) {
      float range = vmax - vmin;
      float scale = (range > 0.f) ? ((float)NBINS / range) : 0.f;
      #pragma unroll
      for (int i2 = 0; i2 < BPL; ++i2) hw[(i2 << 6) | lane] = 0u;
      #pragma unroll
      for (int q = 0; q < 32; ++q) {
        int bb = (int)((sarr[q] - vmin) * scale);
        bb = bb < 0 ? 0 : (bb > NBINS - 1 ? NBINS - 1 : bb);
        atomicAdd(&hw[((bb & 7) << 6) | (bb >> 3)], 1u);
      }
      unsigned A = 0; unsigned hv[BPL];
      #pragma unroll
      for (int i2 = 0; i2 < BPL; ++i2) { hv[i2] = hw[(i2 << 6) | lane]; A += hv[i2]; }
      unsigned ssum = A;
      #pragma unroll
      for (int off = 1; off <= 32; off <<= 1) {
        unsigned u = (unsigned)__shfl_down((int)ssum, off);
        if (lane + off < 64) ssum += u;
      }
      unsigned cum = ssum - A;
      int bsel = -1; int mloc = 0;
      #pragma unroll
      for (int i2 = BPL - 1; i2 >= 0; --i2) {
        unsigned c0 = cum; cum += hv[i2];
        if (bsel < 0 && c0 < (unsigned)nk && cum >= (unsigned)nk) {
          bsel = (lane << 3) | i2; mloc = nk - (int)c0;
        }
      }
      unsigned long long fmk = __ballot(bsel >= 0);
      int srcl = __ffsll(fmk) - 1;
      bsel = __shfl(bsel, srcl);
      int mth = __shfl(mloc, srcl);

      unsigned inbin = 0;
      #pragma unroll
      for (int q = 0; q < 32; ++q) {
        int bb = (int)((sarr[q] - vmin) * scale);
        bb = bb < 0 ? 0 : (bb > NBINS - 1 ? NBINS - 1 : bb);
        if (bb == bsel) inbin |= (1u << q);
      }
      while (true) {
        float cmax = -INFINITY;
        #pragma unroll
        for (int q = 0; q < 32; ++q) if (inbin & (1u << q)) cmax = fmaxf(cmax, sarr[q]);
        #pragma unroll
        for (int off = 32; off >= 1; off >>= 1) cmax = fmaxf(cmax, __shfl_xor(cmax, off));
        int cnt = 0;
        #pragma unroll
        for (int q = 0; q < 32; ++q) if ((inbin & (1u << q)) && sarr[q] == cmax) cnt++;
        #pragma unroll
        for (int off = 32; off >= 1; off >>= 1) cnt += __shfl_xor(cnt, off);
        if (mth <= cnt) { thresh = cmax; break; }
        mth -= cnt;
        #pragma unroll
        for (int q = 0; q < 32; ++q) if ((inbin & (1u << q)) && sarr[q] == cmax) inbin &= ~(1u << q);
      }
    }

    float psum = 0.f;
    #pragma unroll
    for (int q = 0; q < 32; ++q) {
      float p = (sarr[q] >= thresh) ? expf(sarr[q] - vmax) : 0.f;
      sarr[q] = p; psum += p;
    }
    #pragma unroll
    for (int off = 32; off >= 1; off >>= 1) psum += __shfl_xor(psum, off);

    unsigned nkept = 0;
    #pragma unroll
    for (int q = 0; q < 32; ++q) {
      bool keep = sarr[q] > 0.f;
      unsigned long long mk = __ballot(keep);
      if (keep) {
        unsigned idx = nkept + (unsigned)__popcll(mk & ((1ull << lane) - 1ull));
        if (idx < LCAP) {
          kl[idx] = (unsigned)((q >> 2) * 256 + lane * 4 + (q & 3));
          pl[idx] = sarr[q];
        }
      }
      nkept += (unsigned)__popcll(mk);
    }

    float acc0 = 0.f, acc1 = 0.f, acc2 = 0.f, acc3 = 0.f;
    if (nkept <= LCAP) {
      unsigned i = 0;
      for (; i + 4 <= nkept; i += 4) {
        acc0 = fmaf(pl[i+0], Vbh[(size_t)kl[i+0] * DHEAD + lane], acc0);
        acc1 = fmaf(pl[i+1], Vbh[(size_t)kl[i+1] * DHEAD + lane], acc1);
        acc2 = fmaf(pl[i+2], Vbh[(size_t)kl[i+2] * DHEAD + lane], acc2);
        acc3 = fmaf(pl[i+3], Vbh[(size_t)kl[i+3] * DHEAD + lane], acc3);
      }
      for (; i < nkept; ++i)
        acc0 = fmaf(pl[i], Vbh[(size_t)kl[i] * DHEAD + lane], acc0);
    } else {
      #pragma unroll
      for (int q = 0; q < 32; ++q) {
        for (int sl = 0; sl < 64; ++sl) {
          float pp = __shfl(sarr[q], sl);
          if (pp > 0.f)
            acc0 = fmaf(pp, Vbh[(size_t)((q >> 2) * 256 + sl * 4 + (q & 3)) * DHEAD + lane], acc0);
        }
      }
    }
    float accv = (acc0 + acc1) + (acc2 + acc3);
    Out[base + (size_t)(qblk * TQ + row) * DHEAD + lane] = accv / psum;
  }
}

extern "C" void kernel_launch(void* const* d_in, const int* in_sizes, int n_in,
                              void* d_out, int out_size, void* d_ws, size_t ws_size,
                              hipStream_t stream) {
  const float* q  = (const float*)d_in[0];
  const float* k  = (const float*)d_in[1];
  const float* v  = (const float*)d_in[2];
  const int*   nk = (const int*)d_in[3];
  float* out = (float*)d_out;

  size_t srem = (ws_size > VT_BYTES) ? (ws_size - VT_BYTES) : 0;
  size_t maxrows = srem / ((size_t)S_LEN * sizeof(float));
  long long chunk = (long long)(maxrows / 512) * 512;
  if (chunk > NROWS) chunk = NROWS;

  if (chunk >= 512) {
    _Float16* vt = (_Float16*)d_ws;
    float* sws = (float*)((char*)d_ws + VT_BYTES);
    prep_vt<<<dim3(2048), dim3(256), 0, stream>>>(v, vt);
    for (int row0 = 0; row0 < NROWS; row0 += (int)chunk) {
      int rows = (NROWS - row0 < (int)chunk) ? (NROWS - row0) : (int)chunk;
      qk_kernel<<<dim3(rows / 8), dim3(256), 0, stream>>>(q, k, sws, row0);
      selmm_kernel<<<dim3(rows / 16), dim3(1024), 0, stream>>>(sws, vt, nk, out, row0);
    }
  } else {
    dpsa_kernel<<<dim3(8192), dim3(THREADS), 0, stream>>>(q, k, v, nk, out);
  }
}

// Round 21
// 872.081 us; speedup vs baseline: 1.1968x; 1.1968x over previous
//
#include <hip/hip_runtime.h>
#include <math.h>

#define S_LEN 2048
#define DHEAD 64
#define NBINS 512
#define BPL (NBINS / 64)
#define CANDMAX 48
#define NBH 64
#define NROWS (NBH * S_LEN)                 // 32768
#define VT_BYTES (64ull * DHEAD * S_LEN * 2)  // 16 MB fp16 V^T

typedef _Float16 f16x8 __attribute__((ext_vector_type(8)));
typedef _Float16 f16x4 __attribute__((ext_vector_type(4)));
typedef float    f32x4 __attribute__((ext_vector_type(4)));

// ---------------------------------------------------------------------------
// Kernel P: V fp32 -> V^T fp16 via LDS-tile transpose (coalesced both sides).
// Grid = 64 bh x 32 key-tiles; tile = 64 keys x 64 dims.
// ---------------------------------------------------------------------------
__global__ __launch_bounds__(256)
void prep_vt(const float* __restrict__ V, _Float16* __restrict__ VT) {
  __shared__ _Float16 trans[64][72];            // padded: no write conflicts
  const int bh  = (int)blockIdx.x >> 5;
  const int kt  = (int)blockIdx.x & 31;         // key tile
  const int t   = (int)threadIdx.x;
  const int key0 = kt * 64;
  const float* Vb = V + ((size_t)bh * S_LEN + key0) * DHEAD;

  // read: 64 keys x 64 dims fp32, coalesced float4
  {
    const int key = t >> 2;                     // 0..63
    const int dc  = t & 3;                      // 16-dim chunk
    #pragma unroll
    for (int i = 0; i < 4; ++i) {
      int d = dc * 16 + i * 4;
      float4 v4 = *(const float4*)(Vb + (size_t)key * DHEAD + d);
      trans[d + 0][key] = (_Float16)v4.x;
      trans[d + 1][key] = (_Float16)v4.y;
      trans[d + 2][key] = (_Float16)v4.z;
      trans[d + 3][key] = (_Float16)v4.w;
    }
  }
  __syncthreads();

  // write: VT[bh][dim][key0..key0+63], 32B per thread, coalesced per dim
  {
    const int dim = t >> 2;                     // 0..63
    const int kc  = t & 3;                      // 16-key chunk
    _Float16* dst = VT + ((size_t)bh * DHEAD + dim) * S_LEN + key0 + kc * 16;
    f16x8 a, b;
    #pragma unroll
    for (int j = 0; j < 8; ++j) { a[j] = trans[dim][kc * 16 + j];
                                  b[j] = trans[dim][kc * 16 + 8 + j]; }
    *(f16x8*)(dst)     = a;
    *(f16x8*)(dst + 8) = b;
  }
}

// ---------------------------------------------------------------------------
// Kernel A (R16-proven): QK^T via 4-term hi/lo fp16 MFMA. XCD-swizzled.
// Block = 256 thr (4 waves) = 64 q-rows x 256 keys. Grid = rows/8.
// ---------------------------------------------------------------------------
__global__ __launch_bounds__(256, 4)
void qk_kernel(const float* __restrict__ Q, const float* __restrict__ K,
               float* __restrict__ Sws, int row0) {
  __shared__ __align__(16) char kbuf[32768];   // hi 16KB | lo 16KB
  f16x8* Khw = (f16x8*)kbuf;
  f16x8* Klw = (f16x8*)(kbuf + 16384);

  const int tid  = (int)threadIdx.x;
  const int lane = tid & 63;
  const int wid  = tid >> 6;
  const int nxl  = (int)gridDim.x >> 3;
  const int xcd  = (int)blockIdx.x & 7;
  const int lb   = (int)blockIdx.x >> 3;
  const int rb   = lb >> 3;
  const int kb   = lb & 7;                      // key eighth
  const int rowl = xcd * (nxl * 8) + rb * 64 + wid * 16;
  const int rowg = row0 + rowl;
  const int bh   = rowg >> 11;
  const int key0 = kb * 256;

  const int g = lane >> 4;
  const int m = lane & 15;

  f16x8 a_hi0, a_lo0, a_hi1, a_lo1;
  {
    const float* Qrow = Q + (size_t)(rowg + m) * DHEAD;
    float4 qa = *(const float4*)(Qrow + g * 8);
    float4 qb = *(const float4*)(Qrow + g * 8 + 4);
    float4 qc = *(const float4*)(Qrow + 32 + g * 8);
    float4 qd = *(const float4*)(Qrow + 32 + g * 8 + 4);
    float x[16] = {qa.x,qa.y,qa.z,qa.w, qb.x,qb.y,qb.z,qb.w,
                   qc.x,qc.y,qc.z,qc.w, qd.x,qd.y,qd.z,qd.w};
    #pragma unroll
    for (int j = 0; j < 8; ++j) {
      _Float16 h0 = (_Float16)x[j];
      a_hi0[j] = h0;  a_lo0[j] = (_Float16)(x[j] - (float)h0);
      _Float16 h1 = (_Float16)x[8 + j];
      a_hi1[j] = h1;  a_lo1[j] = (_Float16)(x[8 + j] - (float)h1);
    }
  }

  const float* Kb = K + (size_t)bh * (S_LEN * DHEAD);
  float* Srow = Sws + (size_t)rowl * S_LEN;

  const int skey  = tid >> 1;
  const int shalf = tid & 1;
  const int ssw   = skey & 7;

  float4 pf[8];
  {
    const float4* kr = (const float4*)(Kb + (size_t)(key0 + skey) * DHEAD + shalf * 32);
    #pragma unroll
    for (int j = 0; j < 8; ++j) pf[j] = kr[j];
  }

  #pragma unroll
  for (int t = 0; t < 2; ++t) {
    #pragma unroll
    for (int jj = 0; jj < 4; ++jj) {
      float x[8] = {pf[2*jj].x, pf[2*jj].y, pf[2*jj].z, pf[2*jj].w,
                    pf[2*jj+1].x, pf[2*jj+1].y, pf[2*jj+1].z, pf[2*jj+1].w};
      f16x8 hi, lo;
      #pragma unroll
      for (int j = 0; j < 8; ++j) {
        _Float16 h = (_Float16)x[j];
        hi[j] = h;
        lo[j] = (_Float16)(x[j] - (float)h);
      }
      int c = shalf * 4 + jj;
      Khw[skey * 8 + (c ^ ssw)] = hi;
      Klw[skey * 8 + (c ^ ssw)] = lo;
    }
    if (t + 1 < 2) {
      const float4* kr = (const float4*)(Kb + (size_t)(key0 + 128 + skey) * DHEAD + shalf * 32);
      #pragma unroll
      for (int j = 0; j < 8; ++j) pf[j] = kr[j];
    }
    __syncthreads();

    const f16x8* Kh = (const f16x8*)kbuf;
    const f16x8* Kl = (const f16x8*)(kbuf + 16384);
    int slot0 = ( g      ^ (m & 7));
    int slot1 = ((4 + g) ^ (m & 7));
    #pragma unroll
    for (int p = 0; p < 8; ++p) {
      int keyr = p * 16 + m;
      f16x8 b_hi0 = Kh[keyr * 8 + slot0];
      f16x8 b_hi1 = Kh[keyr * 8 + slot1];
      f16x8 b_lo0 = Kl[keyr * 8 + slot0];
      f16x8 b_lo1 = Kl[keyr * 8 + slot1];
      f32x4 acc = {0.f, 0.f, 0.f, 0.f};
      acc = __builtin_amdgcn_mfma_f32_16x16x32_f16(a_hi0, b_hi0, acc, 0, 0, 0);
      acc = __builtin_amdgcn_mfma_f32_16x16x32_f16(a_hi1, b_hi1, acc, 0, 0, 0);
      acc = __builtin_amdgcn_mfma_f32_16x16x32_f16(a_hi0, b_lo0, acc, 0, 0, 0);
      acc = __builtin_amdgcn_mfma_f32_16x16x32_f16(a_hi1, b_lo1, acc, 0, 0, 0);
      acc = __builtin_amdgcn_mfma_f32_16x16x32_f16(a_lo0, b_hi0, acc, 0, 0, 0);
      acc = __builtin_amdgcn_mfma_f32_16x16x32_f16(a_lo1, b_hi1, acc, 0, 0, 0);
      acc = __builtin_amdgcn_mfma_f32_16x16x32_f16(a_lo0, b_lo0, acc, 0, 0, 0);
      acc = __builtin_amdgcn_mfma_f32_16x16x32_f16(a_lo1, b_lo1, acc, 0, 0, 0);
      int col = key0 + t * 128 + p * 16 + m;
      #pragma unroll
      for (int rg = 0; rg < 4; ++rg)
        __builtin_nontemporal_store(acc[rg] * 0.125f,
            &Srow[(size_t)(g * 4 + rg) * S_LEN + col]);
    }
    __syncthreads();
  }
}

// ---------------------------------------------------------------------------
// Kernel B (R16-proven): selection (register sarr, per-wave) + MFMA masked-PV.
// 512 thr = 8 waves; wave w selects rows 2w,2w+1; per-kt P subtile + 4 MFMA.
// ---------------------------------------------------------------------------
__global__ __launch_bounds__(512, 4)
void selmm_kernel(const float* __restrict__ Sws, const _Float16* __restrict__ VT,
                  const int* __restrict__ nkp, float* __restrict__ Out, int row0) {
  __shared__ unsigned histS[8][NBINS];                 // 16 KB
  __shared__ float candS[8][CANDMAX];                  // 1.5 KB
  __shared__ unsigned candCnt[8];
  __shared__ float psumS[16];
  __shared__ __align__(16) char pbuf[8192];            // P tile: 16 rows x 512B
  __shared__ __align__(16) float4 redS[4][64];         // 4 KB kh-reduction

  const int tid  = (int)threadIdx.x;
  const int lane = tid & 63;
  const int wid  = tid >> 6;                           // 0..7
  const int nxl  = (int)gridDim.x >> 3;
  const int xcd  = (int)blockIdx.x & 7;
  const int lbk  = (int)blockIdx.x >> 3;
  const int rowlb = xcd * (nxl * 16) + lbk * 16;       // chunk-local base
  const int rowgb = row0 + rowlb;                      // global base (16-aligned)
  const int bh    = rowgb >> 11;

  int nk = nkp[0];
  if (nk > S_LEN) nk = S_LEN;

  unsigned* hw = histS[wid];
  float sarr[2][32];
  float thr2[2], vmx2[2];

  // ---------------- phase 1: per-wave selection for rows 2w, 2w+1 ----------
  #pragma unroll
  for (int rr = 0; rr < 2; ++rr) {
    const int rloc = wid * 2 + rr;
    {
      const f32x4* S4 = (const f32x4*)(Sws + (size_t)(rowlb + rloc) * S_LEN);
      #pragma unroll
      for (int j = 0; j < 8; ++j) {
        f32x4 v4 = __builtin_nontemporal_load(S4 + j * 64 + lane);
        sarr[rr][j*4+0] = v4[0]; sarr[rr][j*4+1] = v4[1];
        sarr[rr][j*4+2] = v4[2]; sarr[rr][j*4+3] = v4[3];
      }
    }

    float vmax = -INFINITY, vmin = INFINITY;
    #pragma unroll
    for (int q = 0; q < 32; ++q) {
      vmax = fmaxf(vmax, sarr[rr][q]); vmin = fminf(vmin, sarr[rr][q]);
    }
    #pragma unroll
    for (int off = 32; off >= 1; off >>= 1) {
      vmax = fmaxf(vmax, __shfl_xor(vmax, off));
      vmin = fminf(vmin, __shfl_xor(vmin, off));
    }

    float thresh = -INFINITY;
    if (nk > 0) {
      float range = vmax - vmin;
      float scale = (range > 0.f) ? ((float)NBINS / range) : 0.f;
      float boff  = vmin * scale;

      #pragma unroll
      for (int i2 = 0; i2 < BPL; ++i2) hw[(i2 << 6) | lane] = 0u;
      #pragma unroll
      for (int q = 0; q < 32; ++q) {
        int bb = (int)fmaf(sarr[rr][q], scale, -boff);
        bb = bb < 0 ? 0 : (bb > NBINS - 1 ? NBINS - 1 : bb);
        atomicAdd(&hw[((bb & 7) << 6) | (bb >> 3)], 1u);     // transposed bins
      }

      unsigned A = 0;
      #pragma unroll
      for (int i2 = 0; i2 < BPL; ++i2) A += hw[(i2 << 6) | lane];
      unsigned ssum = A;
      #pragma unroll
      for (int off = 1; off <= 32; off <<= 1) {
        unsigned u = (unsigned)__shfl_down((int)ssum, off);
        if (lane + off < 64) ssum += u;
      }
      unsigned cum = ssum - A;
      int bsel = -1; int mloc = 0; int nbloc = 0;
      #pragma unroll
      for (int i2 = BPL - 1; i2 >= 0; --i2) {
        unsigned c0 = cum; cum += hw[(i2 << 6) | lane];
        if (bsel < 0 && c0 < (unsigned)nk && cum >= (unsigned)nk) {
          bsel = (lane << 3) | i2; mloc = nk - (int)c0; nbloc = (int)(cum - c0);
        }
      }
      unsigned long long fm = __ballot(bsel >= 0);
      int srcl = __ffsll(fm) - 1;
      bsel = __shfl(bsel, srcl);
      int mth  = __shfl(mloc, srcl);
      int nbin = __shfl(nbloc, srcl);

      if (nbin <= CANDMAX) {
        if (lane == 0) candCnt[wid] = 0u;
        __builtin_amdgcn_wave_barrier();
        #pragma unroll
        for (int q = 0; q < 32; ++q) {
          int bb = (int)fmaf(sarr[rr][q], scale, -boff);
          bb = bb < 0 ? 0 : (bb > NBINS - 1 ? NBINS - 1 : bb);
          if (bb == bsel) {
            unsigned ix = atomicAdd(&candCnt[wid], 1u);
            if (ix < CANDMAX) candS[wid][ix] = sarr[rr][q];
          }
        }
        __builtin_amdgcn_wave_barrier();
        float prev = INFINITY, kth = -INFINITY;
        int got = 0, guard = 0;
        while (got < mth && guard++ <= CANDMAX) {
          float best = -INFINITY;
          for (int i = 0; i < nbin; ++i) {
            float v = candS[wid][i];
            if (v < prev && v > best) best = v;
          }
          int ce = 0;
          for (int i = 0; i < nbin; ++i) if (candS[wid][i] == best) ce++;
          got += ce; prev = best; kth = best;
        }
        thresh = kth;
      } else {
        // exact shfl-chain fallback (pathological tie mass)
        unsigned inbin = 0;
        #pragma unroll
        for (int q = 0; q < 32; ++q) {
          int bb = (int)fmaf(sarr[rr][q], scale, -boff);
          bb = bb < 0 ? 0 : (bb > NBINS - 1 ? NBINS - 1 : bb);
          if (bb == bsel) inbin |= (1u << q);
        }
        while (true) {
          float cmax = -INFINITY;
          #pragma unroll
          for (int q = 0; q < 32; ++q) if (inbin & (1u << q)) cmax = fmaxf(cmax, sarr[rr][q]);
          #pragma unroll
          for (int off = 32; off >= 1; off >>= 1) cmax = fmaxf(cmax, __shfl_xor(cmax, off));
          int cnt = 0;
          #pragma unroll
          for (int q = 0; q < 32; ++q) if ((inbin & (1u << q)) && sarr[rr][q] == cmax) cnt++;
          #pragma unroll
          for (int off = 32; off >= 1; off >>= 1) cnt += __shfl_xor(cnt, off);
          if (mth <= cnt) { thresh = cmax; break; }
          mth -= cnt;
          #pragma unroll
          for (int q = 0; q < 32; ++q) if ((inbin & (1u << q)) && sarr[rr][q] == cmax) inbin &= ~(1u << q);
        }
      }
    }
    thr2[rr] = thresh; vmx2[rr] = vmax;

    float psum = 0.f;
    #pragma unroll
    for (int q = 0; q < 32; ++q) {
      float s = sarr[rr][q];
      psum += (s >= thresh) ? __expf(s - vmax) : 0.f;
    }
    #pragma unroll
    for (int off = 32; off >= 1; off >>= 1) psum += __shfl_xor(psum, off);
    if (lane == 0) psumS[rloc] = psum;
  }
  __syncthreads();

  // ---------------- phase 2: dense masked-P x V via MFMA -------------------
  const int g   = lane >> 4;
  const int n16 = lane & 15;
  const int dg  = wid & 3;          // dim group: dims dg*16..+15
  const int kh  = wid >> 2;         // key half within 256-tile
  const _Float16* VTb = VT + (size_t)bh * (DHEAD * S_LEN);
  f32x4 acc = {0.f, 0.f, 0.f, 0.f};

  #pragma unroll
  for (int kt = 0; kt < 8; ++kt) {
    // write P tile (fp16, swizzled) for this wave's 2 rows
    #pragma unroll
    for (int rr = 0; rr < 2; ++rr) {
      const int row = wid * 2 + rr;
      f16x4 pv;
      #pragma unroll
      for (int c = 0; c < 4; ++c) {
        float s = sarr[rr][kt * 4 + c];
        float p = (s >= thr2[rr]) ? __expf(s - vmx2[rr]) : 0.f;
        pv[c] = (_Float16)p;
      }
      *(f16x4*)(pbuf + ((row * 512 + lane * 8) ^ ((row & 7) << 4))) = pv;
    }
    __syncthreads();
    #pragma unroll
    for (int s = 0; s < 4; ++s) {
      f16x8 af = *(const f16x8*)(pbuf +
          ((n16 * 512 + kh * 256 + s * 64 + g * 16) ^ ((n16 & 7) << 4)));
      f16x8 bf = *(const f16x8*)(VTb + (size_t)(dg * 16 + n16) * S_LEN +
                                 kt * 256 + kh * 128 + s * 32 + g * 8);
      acc = __builtin_amdgcn_mfma_f32_16x16x32_f16(af, bf, acc, 0, 0, 0);
    }
    __syncthreads();
  }

  // reduce the two key-halves, scale by 1/psum, write out
  if (kh == 1) {
    redS[dg][lane] = make_float4(acc[0], acc[1], acc[2], acc[3]);
  }
  __syncthreads();
  if (kh == 0) {
    float4 o = redS[dg][lane];
    float ov[4] = {o.x, o.y, o.z, o.w};
    #pragma unroll
    for (int rg = 0; rg < 4; ++rg) {
      int row = g * 4 + rg;                      // C-row = P row
      float val = (acc[rg] + ov[rg]) / psumS[row];
      Out[(size_t)(rowgb + row) * DHEAD + dg * 16 + n16] = val;
    }
  }
}

// ---------------------------------------------------------------------------
// Fallback monolithic kernel (round-3, proven) for tiny ws_size
// ---------------------------------------------------------------------------
#define TQ 16
#define KT 128
#define NTILES (S_LEN / KT)
#define THREADS 512
#define LCAP 256
#define SOFF   0
#define KHI    131072
#define KLO    147456
#define HOFF   131072
#define KLOFF  147456
#define PLOFF  155648

__global__ __launch_bounds__(THREADS, 2)
void dpsa_kernel(const float* __restrict__ Q, const float* __restrict__ K,
                 const float* __restrict__ V, const int* __restrict__ nkp,
                 float* __restrict__ Out) {
  __shared__ __align__(16) char smem[163840];
  float* Sf = (float*)(smem + SOFF);

  const int tid  = (int)threadIdx.x;
  const int lane = tid & 63;
  const int wid  = tid >> 6;
  const int bid  = (int)blockIdx.x;
  const int bh   = bid >> 7;
  const int qblk = bid & 127;
  const size_t base = (size_t)bh * (size_t)(S_LEN * DHEAD);
  const float* Kbh = K + base;
  const float* Vbh = V + base;

  int nk = nkp[0];
  if (nk > S_LEN) nk = S_LEN;

  const int g = lane >> 4;
  const int m = lane & 15;

  f16x8 a_hi0, a_lo0, a_hi1, a_lo1;
  {
    const float* Qrow = Q + base + (size_t)(qblk * TQ + m) * DHEAD;
    float4 qa = *(const float4*)(Qrow + g * 8);
    float4 qb = *(const float4*)(Qrow + g * 8 + 4);
    float4 qc = *(const float4*)(Qrow + 32 + g * 8);
    float4 qd = *(const float4*)(Qrow + 32 + g * 8 + 4);
    float x[16] = {qa.x,qa.y,qa.z,qa.w, qb.x,qb.y,qb.z,qb.w,
                   qc.x,qc.y,qc.z,qc.w, qd.x,qd.y,qd.z,qd.w};
    #pragma unroll
    for (int j = 0; j < 8; ++j) {
      _Float16 h0 = (_Float16)x[j];
      a_hi0[j] = h0;  a_lo0[j] = (_Float16)(x[j] - (float)h0);
      _Float16 h1 = (_Float16)x[8 + j];
      a_hi1[j] = h1;  a_lo1[j] = (_Float16)(x[8 + j] - (float)h1);
    }
  }

  const f16x8* Kh = (const f16x8*)(smem + KHI);
  const f16x8* Kl = (const f16x8*)(smem + KLO);
  const int keyl = tid >> 2;
  const int q4i  = tid & 3;
  const int sw   = keyl & 7;

  float4 pf0, pf1, pf2, pf3;
  {
    const float4* Kg4 = (const float4*)Kbh;
    int idx = keyl * 16 + q4i * 4;
    pf0 = Kg4[idx]; pf1 = Kg4[idx + 1]; pf2 = Kg4[idx + 2]; pf3 = Kg4[idx + 3];
  }

  for (int t = 0; t < NTILES; ++t) {
    {
      float x[16] = {pf0.x,pf0.y,pf0.z,pf0.w, pf1.x,pf1.y,pf1.z,pf1.w,
                     pf2.x,pf2.y,pf2.z,pf2.w, pf3.x,pf3.y,pf3.z,pf3.w};
      f16x8 hi0, hi1, lo0, lo1;
      #pragma unroll
      for (int j = 0; j < 8; ++j) {
        _Float16 h0 = (_Float16)x[j];
        hi0[j] = h0;  lo0[j] = (_Float16)(x[j] - (float)h0);
        _Float16 h1 = (_Float16)x[8 + j];
        hi1[j] = h1;  lo1[j] = (_Float16)(x[8 + j] - (float)h1);
      }
      f16x8* KhwF = (f16x8*)(smem + KHI);
      f16x8* KlwF = (f16x8*)(smem + KLO);
      KhwF[keyl * 8 + ((q4i * 2)     ^ sw)] = hi0;
      KhwF[keyl * 8 + ((q4i * 2 + 1) ^ sw)] = hi1;
      KlwF[keyl * 8 + ((q4i * 2)     ^ sw)] = lo0;
      KlwF[keyl * 8 + ((q4i * 2 + 1) ^ sw)] = lo1;
    }
    if (t + 1 < NTILES) {
      const float4* Kg4 = (const float4*)(Kbh + (size_t)(t + 1) * (KT * DHEAD));
      int idx = keyl * 16 + q4i * 4;
      pf0 = Kg4[idx]; pf1 = Kg4[idx + 1]; pf2 = Kg4[idx + 2]; pf3 = Kg4[idx + 3];
    }
    __syncthreads();
    {
      int keyr = wid * 16 + m;
      int s0 = ( g      ^ (m & 7));
      int s1 = ((4 + g) ^ (m & 7));
      f16x8 b_hi0 = Kh[keyr * 8 + s0];
      f16x8 b_hi1 = Kh[keyr * 8 + s1];
      f16x8 b_lo0 = Kl[keyr * 8 + s0];
      f16x8 b_lo1 = Kl[keyr * 8 + s1];
      f32x4 acc = {0.f, 0.f, 0.f, 0.f};
      acc = __builtin_amdgcn_mfma_f32_16x16x32_f16(a_hi0, b_hi0, acc, 0, 0, 0);
      acc = __builtin_amdgcn_mfma_f32_16x16x32_f16(a_hi1, b_hi1, acc, 0, 0, 0);
      acc = __builtin_amdgcn_mfma_f32_16x16x32_f16(a_hi0, b_lo0, acc, 0, 0, 0);
      acc = __builtin_amdgcn_mfma_f32_16x16x32_f16(a_hi1, b_lo1, acc, 0, 0, 0);
      acc = __builtin_amdgcn_mfma_f32_16x16x32_f16(a_lo0, b_hi0, acc, 0, 0, 0);
      acc = __builtin_amdgcn_mfma_f32_16x16x32_f16(a_lo1, b_hi1, acc, 0, 0, 0);
      int keyabs = t * KT + wid * 16 + m;
      #pragma unroll
      for (int rg = 0; rg < 4; ++rg)
        Sf[(size_t)(g * 4 + rg) * S_LEN + keyabs] = acc[rg] * 0.125f;
    }
    __syncthreads();
  }

  unsigned* hw = (unsigned*)(smem + HOFF)  + wid * NBINS;
  unsigned* kl = (unsigned*)(smem + KLOFF) + wid * LCAP;
  float*    pl = (float*)(smem + PLOFF)    + wid * LCAP;
  const float4* S4 = (const float4*)(smem + SOFF);

  for (int rr = 0; rr < 2; ++rr) {
    const int row = wid * 2 + rr;
    float sarr[32];
    #pragma unroll
    for (int j = 0; j < 8; ++j) {
      float4 v4 = S4[row * (S_LEN / 4) + j * 64 + lane];
      sarr[j*4+0] = v4.x; sarr[j*4+1] = v4.y;
      sarr[j*4+2] = v4.z; sarr[j*4+3] = v4.w;
    }

    float vmax = -INFINITY, vmin = INFINITY;
    #pragma unroll
    for (int q = 0; q < 32; ++q) {
      vmax = fmaxf(vmax, sarr[q]); vmin = fminf(vmin, sarr[q]);
    }
    #pragma unroll
    for (int off = 32; off >= 1; off >>= 1) {
      vmax = fmaxf(vmax, __shfl_xor(vmax, off));
      vmin = fminf(vmin, __shfl_xor(vmin, off));
    }

    float thresh = -INFINITY;
    if (nk > 0) {
      float range = vmax - vmin;
      float scale = (range > 0.f) ? ((float)NBINS / range) : 0.f;
      #pragma unroll
      for (int i2 = 0; i2 < BPL; ++i2) hw[(i2 << 6) | lane] = 0u;
      #pragma unroll
      for (int q = 0; q < 32; ++q) {
        int bb = (int)((sarr[q] - vmin) * scale);
        bb = bb < 0 ? 0 : (bb > NBINS - 1 ? NBINS - 1 : bb);
        atomicAdd(&hw[((bb & 7) << 6) | (bb >> 3)], 1u);
      }
      unsigned A = 0; unsigned hv[BPL];
      #pragma unroll
      for (int i2 = 0; i2 < BPL; ++i2) { hv[i2] = hw[(i2 << 6) | lane]; A += hv[i2]; }
      unsigned ssum = A;
      #pragma unroll
      for (int off = 1; off <= 32; off <<= 1) {
        unsigned u = (unsigned)__shfl_down((int)ssum, off);
        if (lane + off < 64) ssum += u;
      }
      unsigned cum = ssum - A;
      int bsel = -1; int mloc = 0;
      #pragma unroll
      for (int i2 = BPL - 1; i2 >= 0; --i2) {
        unsigned c0 = cum; cum += hv[i2];
        if (bsel < 0 && c0 < (unsigned)nk && cum >= (unsigned)nk) {
          bsel = (lane << 3) | i2; mloc = nk - (int)c0;
        }
      }
      unsigned long long fmk = __ballot(bsel >= 0);
      int srcl = __ffsll(fmk) - 1;
      bsel = __shfl(bsel, srcl);
      int mth = __shfl(mloc, srcl);

      unsigned inbin = 0;
      #pragma unroll
      for (int q = 0; q < 32; ++q) {
        int bb = (int)((sarr[q] - vmin) * scale);
        bb = bb < 0 ? 0 : (bb > NBINS - 1 ? NBINS - 1 : bb);
        if (bb == bsel) inbin |= (1u << q);
      }
      while (true) {
        float cmax = -INFINITY;
        #pragma unroll
        for (int q = 0; q < 32; ++q) if (inbin & (1u << q)) cmax = fmaxf(cmax, sarr[q]);
        #pragma unroll
        for (int off = 32; off >= 1; off >>= 1) cmax = fmaxf(cmax, __shfl_xor(cmax, off));
        int cnt = 0;
        #pragma unroll
        for (int q = 0; q < 32; ++q) if ((inbin & (1u << q)) && sarr[q] == cmax) cnt++;
        #pragma unroll
        for (int off = 32; off >= 1; off >>= 1) cnt += __shfl_xor(cnt, off);
        if (mth <= cnt) { thresh = cmax; break; }
        mth -= cnt;
        #pragma unroll
        for (int q = 0; q < 32; ++q) if ((inbin & (1u << q)) && sarr[q] == cmax) inbin &= ~(1u << q);
      }
    }

    float psum = 0.f;
    #pragma unroll
    for (int q = 0; q < 32; ++q) {
      float p = (sarr[q] >= thresh) ? expf(sarr[q] - vmax) : 0.f;
      sarr[q] = p; psum += p;
    }
    #pragma unroll
    for (int off = 32; off >= 1; off >>= 1) psum += __shfl_xor(psum, off);

    unsigned nkept = 0;
    #pragma unroll
    for (int q = 0; q < 32; ++q) {
      bool keep = sarr[q] > 0.f;
      unsigned long long mk = __ballot(keep);
      if (keep) {
        unsigned idx = nkept + (unsigned)__popcll(mk & ((1ull << lane) - 1ull));
        if (idx < LCAP) {
          kl[idx] = (unsigned)((q >> 2) * 256 + lane * 4 + (q & 3));
          pl[idx] = sarr[q];
        }
      }
      nkept += (unsigned)__popcll(mk);
    }

    float acc0 = 0.f, acc1 = 0.f, acc2 = 0.f, acc3 = 0.f;
    if (nkept <= LCAP) {
      unsigned i = 0;
      for (; i + 4 <= nkept; i += 4) {
        acc0 = fmaf(pl[i+0], Vbh[(size_t)kl[i+0] * DHEAD + lane], acc0);
        acc1 = fmaf(pl[i+1], Vbh[(size_t)kl[i+1] * DHEAD + lane], acc1);
        acc2 = fmaf(pl[i+2], Vbh[(size_t)kl[i+2] * DHEAD + lane], acc2);
        acc3 = fmaf(pl[i+3], Vbh[(size_t)kl[i+3] * DHEAD + lane], acc3);
      }
      for (; i < nkept; ++i)
        acc0 = fmaf(pl[i], Vbh[(size_t)kl[i] * DHEAD + lane], acc0);
    } else {
      #pragma unroll
      for (int q = 0; q < 32; ++q) {
        for (int sl = 0; sl < 64; ++sl) {
          float pp = __shfl(sarr[q], sl);
          if (pp > 0.f)
            acc0 = fmaf(pp, Vbh[(size_t)((q >> 2) * 256 + sl * 4 + (q & 3)) * DHEAD + lane], acc0);
        }
      }
    }
    float accv = (acc0 + acc1) + (acc2 + acc3);
    Out[base + (size_t)(qblk * TQ + row) * DHEAD + lane] = accv / psum;
  }
}

extern "C" void kernel_launch(void* const* d_in, const int* in_sizes, int n_in,
                              void* d_out, int out_size, void* d_ws, size_t ws_size,
                              hipStream_t stream) {
  const float* q  = (const float*)d_in[0];
  const float* k  = (const float*)d_in[1];
  const float* v  = (const float*)d_in[2];
  const int*   nk = (const int*)d_in[3];
  float* out = (float*)d_out;

  size_t srem = (ws_size > VT_BYTES) ? (ws_size - VT_BYTES) : 0;
  size_t maxrows = srem / ((size_t)S_LEN * sizeof(float));
  long long chunk = (long long)(maxrows / 512) * 512;
  if (chunk > NROWS) chunk = NROWS;

  if (chunk >= 512) {
    _Float16* vt = (_Float16*)d_ws;
    float* sws = (float*)((char*)d_ws + VT_BYTES);
    prep_vt<<<dim3(2048), dim3(256), 0, stream>>>(v, vt);
    for (int row0 = 0; row0 < NROWS; row0 += (int)chunk) {
      int rows = (NROWS - row0 < (int)chunk) ? (NROWS - row0) : (int)chunk;
      qk_kernel<<<dim3(rows / 8), dim3(256), 0, stream>>>(q, k, sws, row0);
      selmm_kernel<<<dim3(rows / 16), dim3(512), 0, stream>>>(sws, vt, nk, out, row0);
    }
  } else {
    dpsa_kernel<<<dim3(8192), dim3(THREADS), 0, stream>>>(q, k, v, nk, out);
  }
}